// Round 2
// baseline (963.606 us; speedup 1.0000x reference)
//
#include <hip/hip_runtime.h>

// Quantize_78365973283370: VQ with argmax (faithful source bug: farthest cluster).
// d_in[0] = inputs [8,32,32,128] f32 (N=8192 x D=128)
// d_in[1] = cluster_mean [128,10000] f32 (column e = cluster vector)
// out (f32 concat): quantize[8192*128] | cluster_index[8192] (as float) | diff[8192]
//
// Strategy: f32 score pass (score = ||c||^2 - 2 s.c ; s-norm constant per row, drops out
// of argmax). Track top1(val,idx)+top2(val); if gap < MARGIN, f64 refine pass recomputes
// that row exactly (matches R1's proven-exact f64 result). Expected flagged ~25/8192.

#define NSAMP 8192
#define NEMB  10000
#define DIM   128
#define NS    8            // samples per block (main)
#define TPB   256
#define CHUNK (TPB * 8)    // 2048 columns per chunk, 8 cols/thread
#define MARGIN 0.02f

// ---------------- prep: cluster norms in f64 (+f32 copy) ----------------
__global__ __launch_bounds__(TPB) void prep_c2(const float* __restrict__ cm,
                                               double* __restrict__ c2d,
                                               float* __restrict__ c2f) {
    int e = blockIdx.x * TPB + threadIdx.x;
    if (e >= NEMB) return;
    double a = 0.0;
#pragma unroll 8
    for (int d = 0; d < DIM; ++d) {
        double v = (double)cm[(size_t)d * NEMB + e];
        a = fma(v, v, a);
    }
    c2d[e] = a;
    c2f[e] = (float)a;
}

// ---------------- main f32 pass ----------------
__global__ __launch_bounds__(TPB) void vq_main32(
    const float* __restrict__ cm, const float* __restrict__ smp,
    const float* __restrict__ c2f,
    float* __restrict__ out_q, float* __restrict__ out_idx, float* __restrict__ out_diff,
    int* __restrict__ flag)
{
    const int tid = threadIdx.x;
    const int s0 = blockIdx.x * NS;

    __shared__ float ssv[DIM][NS];     // [d][s] sample broadcast tile, 4 KB
#pragma unroll
    for (int i = 0; i < (DIM * NS) / TPB; ++i) {   // 4 iters, coalesced reads
        int gid = i * TPB + tid;
        int n = gid >> 7;          // /DIM
        int d = gid & (DIM - 1);
        ssv[d][n] = smp[(size_t)(s0 + n) * DIM + d];
    }
    __syncthreads();

    float v1[NS], v2[NS];
    int   i1[NS];
#pragma unroll
    for (int s = 0; s < NS; ++s) { v1[s] = -3.0e38f; v2[s] = -3.0e38f; i1[s] = 0; }

    for (int e0 = 0; e0 < NEMB; e0 += CHUNK) {     // 5 chunks
        const int b0 = e0 + tid * 4;
        const int b1 = b0 + TPB * 4;               // +1024
        const int cb0 = (b0 > NEMB - 4) ? (NEMB - 4) : b0;   // clamp only when whole group OOB
        const int cb1 = (b1 > NEMB - 4) ? (NEMB - 4) : b1;
        const float* p0 = cm + cb0;
        const float* p1 = cm + cb1;

        float acc[NS][8];
#pragma unroll
        for (int s = 0; s < NS; ++s)
#pragma unroll
            for (int k = 0; k < 8; ++k) acc[s][k] = 0.0f;

#pragma unroll 2
        for (int d = 0; d < DIM; ++d) {
            float4 a = *(const float4*)(p0 + (size_t)d * NEMB);
            float4 b = *(const float4*)(p1 + (size_t)d * NEMB);
            const float4* sp = (const float4*)&ssv[d][0];
            float4 sl = sp[0], sh = sp[1];         // ds_read_b128 x2, broadcast
            float sv_[8] = {sl.x, sl.y, sl.z, sl.w, sh.x, sh.y, sh.z, sh.w};
#pragma unroll
            for (int s = 0; s < NS; ++s) {
                float sv = sv_[s];
                acc[s][0] = fmaf(a.x, sv, acc[s][0]);
                acc[s][1] = fmaf(a.y, sv, acc[s][1]);
                acc[s][2] = fmaf(a.z, sv, acc[s][2]);
                acc[s][3] = fmaf(a.w, sv, acc[s][3]);
                acc[s][4] = fmaf(b.x, sv, acc[s][4]);
                acc[s][5] = fmaf(b.y, sv, acc[s][5]);
                acc[s][6] = fmaf(b.z, sv, acc[s][6]);
                acc[s][7] = fmaf(b.w, sv, acc[s][7]);
            }
        }

        float4 c0 = *(const float4*)(c2f + cb0);
        float4 c1 = *(const float4*)(c2f + cb1);
        float cc[8] = {c0.x, c0.y, c0.z, c0.w, c1.x, c1.y, c1.z, c1.w};
#pragma unroll
        for (int k = 0; k < 8; ++k) {
            const int ec = (k < 4) ? (b0 + k) : (b1 + k - 4);   // ascending in k
            if (ec < NEMB) {
#pragma unroll
                for (int s = 0; s < NS; ++s) {
                    float sc = fmaf(-2.0f, acc[s][k], cc[k]);
                    if (sc > v1[s]) { v2[s] = v1[s]; v1[s] = sc; i1[s] = ec; }
                    else if (sc > v2[s]) { v2[s] = sc; }
                }
            }
        }
    }

    // wave butterfly merge: max val (tie -> smaller idx), global second-max
#pragma unroll
    for (int s = 0; s < NS; ++s) {
#pragma unroll
        for (int m = 1; m < 64; m <<= 1) {
            float ov1 = __shfl_xor(v1[s], m, 64);
            int   oi1 = __shfl_xor(i1[s], m, 64);
            float ov2 = __shfl_xor(v2[s], m, 64);
            float nv2 = fmaxf(fminf(v1[s], ov1), fmaxf(v2[s], ov2));
            if (ov1 > v1[s] || (ov1 == v1[s] && oi1 < i1[s])) { v1[s] = ov1; i1[s] = oi1; }
            v2[s] = nv2;
        }
    }

    __shared__ float swv1[TPB / 64][NS], swv2[TPB / 64][NS];
    __shared__ int   swi[TPB / 64][NS];
    __shared__ int   fin[NS];
    const int lane = tid & 63, wav = tid >> 6;
    if (lane == 0) {
#pragma unroll
        for (int s = 0; s < NS; ++s) { swv1[wav][s] = v1[s]; swi[wav][s] = i1[s]; swv2[wav][s] = v2[s]; }
    }
    __syncthreads();
    if (tid < NS) {
        const int s = tid;
        float bv1 = swv1[0][s]; int bi = swi[0][s]; float bv2 = swv2[0][s];
#pragma unroll
        for (int w = 1; w < TPB / 64; ++w) {
            float av1 = swv1[w][s]; int ai = swi[w][s]; float av2 = swv2[w][s];
            float nv2 = fmaxf(fminf(bv1, av1), fmaxf(bv2, av2));
            if (av1 > bv1 || (av1 == bv1 && ai < bi)) { bv1 = av1; bi = ai; }
            bv2 = nv2;
        }
        fin[s] = bi;
        out_idx[s0 + s] = (float)bi;
        flag[s0 + s] = (bv1 - bv2 < MARGIN) ? 1 : 0;
    }
    __syncthreads();

    // epilogue: gather quantize + diff (32 threads/sample, 4 dims each)
    {
        const int s  = tid >> 5;
        const int d0 = (tid & 31) * 4;
        const int e  = fin[s];
        float a = 0.0f;
#pragma unroll
        for (int j = 0; j < 4; ++j) {
            int d = d0 + j;
            float q = cm[(size_t)d * NEMB + e];
            float x = smp[(size_t)(s0 + s) * DIM + d];
            out_q[(size_t)(s0 + s) * DIM + d] = q;
            float t = x - q;
            a = fmaf(t, t, a);
        }
#pragma unroll
        for (int m = 1; m < 32; m <<= 1) a += __shfl_xor(a, m, 64);
        if ((tid & 31) == 0) out_diff[s0 + s] = a * (1.0f / DIM);
    }
}

// ---------------- f64 refine for flagged samples ----------------
#define RSPB 32   // samples scanned per refine block
__global__ __launch_bounds__(TPB) void vq_refine(
    const float* __restrict__ cm, const float* __restrict__ smp,
    const double* __restrict__ c2d, const int* __restrict__ flag,
    float* __restrict__ out_q, float* __restrict__ out_idx, float* __restrict__ out_diff)
{
    const int tid = threadIdx.x;
    const int lane = tid & 63, wav = tid >> 6;
    __shared__ double sv[DIM];
    __shared__ double wv[TPB / 64];
    __shared__ int    we[TPB / 64];
    __shared__ float  dsum[TPB / 64];
    __shared__ int    fin;

    for (int s = blockIdx.x * RSPB; s < blockIdx.x * RSPB + RSPB; ++s) {
        if (!flag[s]) continue;          // block-uniform
        __syncthreads();
        if (tid < DIM) sv[tid] = (double)smp[(size_t)s * DIM + tid];
        __syncthreads();

        double bv = -1.0e300; int be = 0;
        for (int e = tid; e < NEMB; e += TPB) {     // e ascending per thread
            double dot = 0.0;
#pragma unroll 8
            for (int d = 0; d < DIM; ++d)
                dot = fma((double)cm[(size_t)d * NEMB + e], sv[d], dot);
            double sc = fma(-2.0, dot, c2d[e]);
            if (sc > bv) { bv = sc; be = e; }
        }
#pragma unroll
        for (int m = 1; m < 64; m <<= 1) {
            double ov = __shfl_xor(bv, m, 64);
            int    oe = __shfl_xor(be, m, 64);
            if (ov > bv || (ov == bv && oe < be)) { bv = ov; be = oe; }
        }
        if (lane == 0) { wv[wav] = bv; we[wav] = be; }
        __syncthreads();
        if (tid == 0) {
            double v = wv[0]; int e = we[0];
#pragma unroll
            for (int w = 1; w < TPB / 64; ++w)
                if (wv[w] > v || (wv[w] == v && we[w] < e)) { v = wv[w]; e = we[w]; }
            fin = e;
            out_idx[s] = (float)e;
        }
        __syncthreads();
        const int e = fin;
        float t2 = 0.0f;
        if (tid < DIM) {
            float q = cm[(size_t)tid * NEMB + e];
            float x = smp[(size_t)s * DIM + tid];
            out_q[(size_t)s * DIM + tid] = q;
            float t = x - q;
            t2 = t * t;
        }
#pragma unroll
        for (int m = 1; m < 64; m <<= 1) t2 += __shfl_xor(t2, m, 64);
        if (lane == 0) dsum[wav] = t2;
        __syncthreads();
        if (tid == 0) out_diff[s] = (dsum[0] + dsum[1] + dsum[2] + dsum[3]) * (1.0f / DIM);
        __syncthreads();
    }
}

extern "C" void kernel_launch(void* const* d_in, const int* in_sizes, int n_in,
                              void* d_out, int out_size, void* d_ws, size_t ws_size,
                              hipStream_t stream) {
    const float* smp = (const float*)d_in[0];   // [8192,128]
    const float* cm  = (const float*)d_in[1];   // [128,10000]

    float* out      = (float*)d_out;
    float* out_q    = out;
    float* out_idx  = out + (size_t)NSAMP * DIM;
    float* out_diff = out_idx + NSAMP;

    char* ws = (char*)d_ws;
    double* c2d  = (double*)ws;                          // 80000 B (16B aligned)
    float*  c2f  = (float*)(ws + 80000);                 // 40000 B
    int*    flag = (int*)(ws + 120000);                  // 32768 B

    prep_c2<<<(NEMB + TPB - 1) / TPB, TPB, 0, stream>>>(cm, c2d, c2f);
    vq_main32<<<NSAMP / NS, TPB, 0, stream>>>(cm, smp, c2f, out_q, out_idx, out_diff, flag);
    vq_refine<<<NSAMP / RSPB, TPB, 0, stream>>>(cm, smp, c2d, flag, out_q, out_idx, out_diff);
}

// Round 4
// 761.454 us; speedup vs baseline: 1.2655x; 1.2655x over previous
//
#include <hip/hip_runtime.h>

// Quantize_78365973283370: VQ with argmax (faithful source bug: farthest cluster).
// d_in[0] = inputs [8,32,32,128] f32 (N=8192 x D=128)
// d_in[1] = cluster_mean [128,10000] f32 (column e = cluster vector)
// out (f32 concat): quantize[8192*128] | cluster_index[8192] (as float) | diff[8192]
//
// f32 score pass (score = ||c||^2 - 2 s.c). Track top1(val,idx)+top2(val); samples with
// gap < MARGIN get an IN-BLOCK exact f64 rescan (matches R1's proven-exact f64 result).
// NS=16 samples/block -> 8 flop/byte, compute-bound (~133 us f32 FMA floor).

#define NSAMP 8192
#define NEMB  10000
#define DIM   128
#define NS    16           // samples per block
#define TPB   256
#define CHUNK (TPB * 4)    // 1024 columns per chunk, 4 cols/thread -> 10 chunks
#define MARGIN 0.02f

// ---------------- prep: cluster norms in f64 (+f32 copy) ----------------
__global__ __launch_bounds__(TPB) void prep_c2(const float* __restrict__ cm,
                                               double* __restrict__ c2d,
                                               float* __restrict__ c2f) {
    int e = blockIdx.x * TPB + threadIdx.x;
    if (e >= NEMB) return;
    double a = 0.0;
#pragma unroll 8
    for (int d = 0; d < DIM; ++d) {
        double v = (double)cm[(size_t)d * NEMB + e];
        a = fma(v, v, a);
    }
    c2d[e] = a;
    c2f[e] = (float)a;
}

// ---------------- fused main pass + in-block f64 refine ----------------
__global__ __launch_bounds__(TPB) void vq_main32(
    const float* __restrict__ cm, const float* __restrict__ smp,
    const float* __restrict__ c2f, const double* __restrict__ c2d,
    float* __restrict__ out_q, float* __restrict__ out_idx, float* __restrict__ out_diff)
{
    const int tid = threadIdx.x;
    const int s0 = blockIdx.x * NS;
    const int lane = tid & 63, wav = tid >> 6;

    __shared__ float ssv[DIM][NS];     // [d][s] sample broadcast tile, 8 KB
#pragma unroll
    for (int i = 0; i < (DIM * NS) / TPB; ++i) {   // 8 iters, coalesced reads
        int gid = i * TPB + tid;
        int n = gid >> 7;          // /DIM
        int d = gid & (DIM - 1);
        ssv[d][n] = smp[(size_t)(s0 + n) * DIM + d];
    }
    __syncthreads();

    float v1[NS], v2[NS];
    int   i1[NS];
#pragma unroll
    for (int s = 0; s < NS; ++s) { v1[s] = -3.0e38f; v2[s] = -3.0e38f; i1[s] = 0; }

#pragma unroll 1
    for (int e0 = 0; e0 < NEMB; e0 += CHUNK) {     // 10 chunks
        const int b0 = e0 + tid * 4;
        const int cb0 = (b0 > NEMB - 4) ? (NEMB - 4) : b0;   // clamp (tail chunk)
        const float* p0 = cm + cb0;

        float acc[NS][4];
#pragma unroll
        for (int s = 0; s < NS; ++s)
#pragma unroll
            for (int k = 0; k < 4; ++k) acc[s][k] = 0.0f;

#pragma unroll 2
        for (int d = 0; d < DIM; ++d) {
            float4 a = *(const float4*)(p0 + (size_t)d * NEMB);
            const float4* sp = (const float4*)&ssv[d][0];    // broadcast ds_read_b128 x4
            float4 q0 = sp[0], q1 = sp[1], q2 = sp[2], q3 = sp[3];
            float sv_[NS] = {q0.x, q0.y, q0.z, q0.w, q1.x, q1.y, q1.z, q1.w,
                             q2.x, q2.y, q2.z, q2.w, q3.x, q3.y, q3.z, q3.w};
#pragma unroll
            for (int s = 0; s < NS; ++s) {
                float sv = sv_[s];
                acc[s][0] = fmaf(a.x, sv, acc[s][0]);
                acc[s][1] = fmaf(a.y, sv, acc[s][1]);
                acc[s][2] = fmaf(a.z, sv, acc[s][2]);
                acc[s][3] = fmaf(a.w, sv, acc[s][3]);
            }
        }

        float4 c0 = *(const float4*)(c2f + cb0);
        float cc[4] = {c0.x, c0.y, c0.z, c0.w};
#pragma unroll
        for (int k = 0; k < 4; ++k) {
            const int ec = b0 + k;                 // ascending in k
            if (ec < NEMB) {
#pragma unroll
                for (int s = 0; s < NS; ++s) {
                    float sc = fmaf(-2.0f, acc[s][k], cc[k]);
                    if (sc > v1[s]) { v2[s] = v1[s]; v1[s] = sc; i1[s] = ec; }
                    else if (sc > v2[s]) { v2[s] = sc; }
                }
            }
        }
    }

    // wave butterfly merge: max val (tie -> smaller idx), global second-max
#pragma unroll
    for (int s = 0; s < NS; ++s) {
#pragma unroll
        for (int m = 1; m < 64; m <<= 1) {
            float ov1 = __shfl_xor(v1[s], m, 64);
            int   oi1 = __shfl_xor(i1[s], m, 64);
            float ov2 = __shfl_xor(v2[s], m, 64);
            float nv2 = fmaxf(fminf(v1[s], ov1), fmaxf(v2[s], ov2));
            if (ov1 > v1[s] || (ov1 == v1[s] && oi1 < i1[s])) { v1[s] = ov1; i1[s] = oi1; }
            v2[s] = nv2;
        }
    }

    __shared__ float swv1[TPB / 64][NS], swv2[TPB / 64][NS];
    __shared__ int   swi[TPB / 64][NS];
    __shared__ int   fin[NS];
    __shared__ int   sflag[NS];
    if (lane == 0) {
#pragma unroll
        for (int s = 0; s < NS; ++s) { swv1[wav][s] = v1[s]; swi[wav][s] = i1[s]; swv2[wav][s] = v2[s]; }
    }
    __syncthreads();
    if (tid < NS) {
        const int s = tid;
        float bv1 = swv1[0][s]; int bi = swi[0][s]; float bv2 = swv2[0][s];
#pragma unroll
        for (int w = 1; w < TPB / 64; ++w) {
            float av1 = swv1[w][s]; int ai = swi[w][s]; float av2 = swv2[w][s];
            float nv2 = fmaxf(fminf(bv1, av1), fmaxf(bv2, av2));
            if (av1 > bv1 || (av1 == bv1 && ai < bi)) { bv1 = av1; bi = ai; }
            bv2 = nv2;
        }
        fin[s] = bi;
        sflag[s] = (bv1 - bv2 < MARGIN) ? 1 : 0;
    }
    __syncthreads();

    // ---- in-block exact f64 rescan for flagged samples (rare) ----
    __shared__ double svd[DIM];
    __shared__ double rwv[TPB / 64];
    __shared__ int    rwe[TPB / 64];
#pragma unroll 1
    for (int s = 0; s < NS; ++s) {
        if (!sflag[s]) continue;               // block-uniform (LDS)
        if (tid < DIM) svd[tid] = (double)smp[(size_t)(s0 + s) * DIM + tid];
        __syncthreads();
        double bv = -1.0e300; int be = 0;
#pragma unroll 1
        for (int e0 = tid * 4; e0 < NEMB; e0 += TPB * 4) {   // ascending e per thread
            double dot[4] = {0.0, 0.0, 0.0, 0.0};
#pragma unroll 8
            for (int d = 0; d < DIM; ++d) {
                float4 cv = *(const float4*)(cm + (size_t)d * NEMB + e0);
                double sd = svd[d];
                dot[0] = fma((double)cv.x, sd, dot[0]);
                dot[1] = fma((double)cv.y, sd, dot[1]);
                dot[2] = fma((double)cv.z, sd, dot[2]);
                dot[3] = fma((double)cv.w, sd, dot[3]);
            }
#pragma unroll
            for (int k = 0; k < 4; ++k) {
                int e = e0 + k;
                double sc = fma(-2.0, dot[k], c2d[e]);
                if (sc > bv) { bv = sc; be = e; }
            }
        }
#pragma unroll
        for (int m = 1; m < 64; m <<= 1) {
            double ov = __shfl_xor(bv, m, 64);
            int    oe = __shfl_xor(be, m, 64);
            if (ov > bv || (ov == bv && oe < be)) { bv = ov; be = oe; }
        }
        if (lane == 0) { rwv[wav] = bv; rwe[wav] = be; }
        __syncthreads();
        if (tid == 0) {
            double v = rwv[0]; int e = rwe[0];
#pragma unroll
            for (int w = 1; w < TPB / 64; ++w)
                if (rwv[w] > v || (rwv[w] == v && rwe[w] < e)) { v = rwv[w]; e = rwe[w]; }
            fin[s] = e;
        }
        __syncthreads();
    }
    __syncthreads();

    // ---- epilogue: idx + gather quantize + diff (16 threads/sample, 8 dims each) ----
    {
        const int s  = tid >> 4;
        const int d0 = (tid & 15) * 8;
        const int e  = fin[s];
        float a = 0.0f;
#pragma unroll
        for (int j = 0; j < 8; ++j) {
            int d = d0 + j;
            float q = cm[(size_t)d * NEMB + e];
            float x = smp[(size_t)(s0 + s) * DIM + d];
            out_q[(size_t)(s0 + s) * DIM + d] = q;
            float t = x - q;
            a = fmaf(t, t, a);
        }
#pragma unroll
        for (int m = 1; m < 16; m <<= 1) a += __shfl_xor(a, m, 64);
        if ((tid & 15) == 0) out_diff[s0 + s] = a * (1.0f / DIM);
        if (tid < NS) out_idx[s0 + tid] = (float)fin[tid];
    }
}

extern "C" void kernel_launch(void* const* d_in, const int* in_sizes, int n_in,
                              void* d_out, int out_size, void* d_ws, size_t ws_size,
                              hipStream_t stream) {
    const float* smp = (const float*)d_in[0];   // [8192,128]
    const float* cm  = (const float*)d_in[1];   // [128,10000]

    float* out      = (float*)d_out;
    float* out_q    = out;
    float* out_idx  = out + (size_t)NSAMP * DIM;
    float* out_diff = out_idx + NSAMP;

    char* ws = (char*)d_ws;
    double* c2d = (double*)ws;                  // 80000 B
    float*  c2f = (float*)(ws + 80000);         // 40000 B

    prep_c2<<<(NEMB + TPB - 1) / TPB, TPB, 0, stream>>>(cm, c2d, c2f);
    vq_main32<<<NSAMP / NS, TPB, 0, stream>>>(cm, smp, c2f, c2d, out_q, out_idx, out_diff);
}

// Round 6
// 458.704 us; speedup vs baseline: 2.1007x; 1.6600x over previous
//
#include <hip/hip_runtime.h>

// Quantize_78365973283370: VQ with argmax (faithful source bug: farthest cluster).
// d_in[0] = inputs [8,32,32,128] f32 (N=8192 x D=128)
// d_in[1] = cluster_mean [128,10000] f32 (column e = cluster vector)
// out (f32 concat): quantize[8192*128] | cluster_index[8192] (as float) | diff[8192]
//
// f32 score pass (score = ||c||^2 - 2 s.c). Track top1(val,idx)+top2(val); samples with
// gap < MARGIN get an IN-BLOCK exact f64 rescan (matches R1's proven-exact f64 result).
// R5: TPB 256->512 (same 512 blocks => 16 waves/CU instead of 8) to fix the 18%
// occupancy / 43% VALUBusy latency-bound stall seen in R4.

#define NSAMP 8192
#define NEMB  10000
#define DIM   128
#define NS    16           // samples per block
#define TPB   512          // 8 waves/block, 2 blocks/CU -> 4 waves/SIMD
#define PREP_TPB 256
#define CHUNK (TPB * 4)    // 2048 columns per chunk, 4 cols/thread -> 5 chunks
#define MARGIN 0.02f

// ---------------- prep: cluster norms in f64 (+f32 copy) ----------------
__global__ __launch_bounds__(PREP_TPB) void prep_c2(const float* __restrict__ cm,
                                                    double* __restrict__ c2d,
                                                    float* __restrict__ c2f) {
    int e = blockIdx.x * PREP_TPB + threadIdx.x;
    if (e >= NEMB) return;
    double a = 0.0;
#pragma unroll 8
    for (int d = 0; d < DIM; ++d) {
        double v = (double)cm[(size_t)d * NEMB + e];
        a = fma(v, v, a);
    }
    c2d[e] = a;
    c2f[e] = (float)a;
}

// ---------------- fused main pass + in-block f64 refine ----------------
__global__ __launch_bounds__(TPB, 4) void vq_main32(
    const float* __restrict__ cm, const float* __restrict__ smp,
    const float* __restrict__ c2f, const double* __restrict__ c2d,
    float* __restrict__ out_q, float* __restrict__ out_idx, float* __restrict__ out_diff)
{
    const int tid = threadIdx.x;
    const int s0 = blockIdx.x * NS;
    const int lane = tid & 63, wav = tid >> 6;

    __shared__ float ssv[DIM][NS];     // [d][s] sample broadcast tile, 8 KB
#pragma unroll
    for (int i = 0; i < (DIM * NS) / TPB; ++i) {   // 4 iters, coalesced reads
        int gid = i * TPB + tid;
        int n = gid >> 7;          // /DIM
        int d = gid & (DIM - 1);
        ssv[d][n] = smp[(size_t)(s0 + n) * DIM + d];
    }
    __syncthreads();

    float v1[NS], v2[NS];
    int   i1[NS];
#pragma unroll
    for (int s = 0; s < NS; ++s) { v1[s] = -3.0e38f; v2[s] = -3.0e38f; i1[s] = 0; }

#pragma unroll 1
    for (int e0 = 0; e0 < NEMB; e0 += CHUNK) {     // 5 chunks
        const int b0 = e0 + tid * 4;
        const int cb0 = (b0 > NEMB - 4) ? (NEMB - 4) : b0;   // clamp (tail chunk)
        const float* p0 = cm + cb0;

        float acc[NS][4];
#pragma unroll
        for (int s = 0; s < NS; ++s)
#pragma unroll
            for (int k = 0; k < 4; ++k) acc[s][k] = 0.0f;

#pragma unroll 2
        for (int d = 0; d < DIM; ++d) {
            float4 a = *(const float4*)(p0 + (size_t)d * NEMB);
            const float4* sp = (const float4*)&ssv[d][0];    // broadcast ds_read_b128 x4
            float4 q0 = sp[0], q1 = sp[1], q2 = sp[2], q3 = sp[3];
            float sv_[NS] = {q0.x, q0.y, q0.z, q0.w, q1.x, q1.y, q1.z, q1.w,
                             q2.x, q2.y, q2.z, q2.w, q3.x, q3.y, q3.z, q3.w};
#pragma unroll
            for (int s = 0; s < NS; ++s) {
                float sv = sv_[s];
                acc[s][0] = fmaf(a.x, sv, acc[s][0]);
                acc[s][1] = fmaf(a.y, sv, acc[s][1]);
                acc[s][2] = fmaf(a.z, sv, acc[s][2]);
                acc[s][3] = fmaf(a.w, sv, acc[s][3]);
            }
        }

        float4 c0 = *(const float4*)(c2f + cb0);
        float cc[4] = {c0.x, c0.y, c0.z, c0.w};
#pragma unroll
        for (int k = 0; k < 4; ++k) {
            const int ec = b0 + k;                 // ascending in k
            if (ec < NEMB) {
#pragma unroll
                for (int s = 0; s < NS; ++s) {
                    float sc = fmaf(-2.0f, acc[s][k], cc[k]);
                    if (sc > v1[s]) { v2[s] = v1[s]; v1[s] = sc; i1[s] = ec; }
                    else if (sc > v2[s]) { v2[s] = sc; }
                }
            }
        }
    }

    // wave butterfly merge: max val (tie -> smaller idx), global second-max
#pragma unroll
    for (int s = 0; s < NS; ++s) {
#pragma unroll
        for (int m = 1; m < 64; m <<= 1) {
            float ov1 = __shfl_xor(v1[s], m, 64);
            int   oi1 = __shfl_xor(i1[s], m, 64);
            float ov2 = __shfl_xor(v2[s], m, 64);
            float nv2 = fmaxf(fminf(v1[s], ov1), fmaxf(v2[s], ov2));
            if (ov1 > v1[s] || (ov1 == v1[s] && oi1 < i1[s])) { v1[s] = ov1; i1[s] = oi1; }
            v2[s] = nv2;
        }
    }

    __shared__ float swv1[TPB / 64][NS], swv2[TPB / 64][NS];
    __shared__ int   swi[TPB / 64][NS];
    __shared__ int   fin[NS];
    __shared__ int   sflag[NS];
    if (lane == 0) {
#pragma unroll
        for (int s = 0; s < NS; ++s) { swv1[wav][s] = v1[s]; swi[wav][s] = i1[s]; swv2[wav][s] = v2[s]; }
    }
    __syncthreads();
    if (tid < NS) {
        const int s = tid;
        float bv1 = swv1[0][s]; int bi = swi[0][s]; float bv2 = swv2[0][s];
#pragma unroll
        for (int w = 1; w < TPB / 64; ++w) {
            float av1 = swv1[w][s]; int ai = swi[w][s]; float av2 = swv2[w][s];
            float nv2 = fmaxf(fminf(bv1, av1), fmaxf(bv2, av2));
            if (av1 > bv1 || (av1 == bv1 && ai < bi)) { bv1 = av1; bi = ai; }
            bv2 = nv2;
        }
        fin[s] = bi;
        sflag[s] = (bv1 - bv2 < MARGIN) ? 1 : 0;
    }
    __syncthreads();

    // ---- in-block exact f64 rescan for flagged samples (rare) ----
    __shared__ double svd[DIM];
    __shared__ double rwv[TPB / 64];
    __shared__ int    rwe[TPB / 64];
#pragma unroll 1
    for (int s = 0; s < NS; ++s) {
        if (!sflag[s]) continue;               // block-uniform (LDS)
        if (tid < DIM) svd[tid] = (double)smp[(size_t)(s0 + s) * DIM + tid];
        __syncthreads();
        double bv = -1.0e300; int be = 0;
#pragma unroll 1
        for (int e0 = tid * 4; e0 < NEMB; e0 += TPB * 4) {   // ascending e per thread
            double dot[4] = {0.0, 0.0, 0.0, 0.0};
#pragma unroll 8
            for (int d = 0; d < DIM; ++d) {
                float4 cv = *(const float4*)(cm + (size_t)d * NEMB + e0);
                double sd = svd[d];
                dot[0] = fma((double)cv.x, sd, dot[0]);
                dot[1] = fma((double)cv.y, sd, dot[1]);
                dot[2] = fma((double)cv.z, sd, dot[2]);
                dot[3] = fma((double)cv.w, sd, dot[3]);
            }
#pragma unroll
            for (int k = 0; k < 4; ++k) {
                int e = e0 + k;
                double sc = fma(-2.0, dot[k], c2d[e]);
                if (sc > bv) { bv = sc; be = e; }
            }
        }
#pragma unroll
        for (int m = 1; m < 64; m <<= 1) {
            double ov = __shfl_xor(bv, m, 64);
            int    oe = __shfl_xor(be, m, 64);
            if (ov > bv || (ov == bv && oe < be)) { bv = ov; be = oe; }
        }
        if (lane == 0) { rwv[wav] = bv; rwe[wav] = be; }
        __syncthreads();
        if (tid == 0) {
            double v = rwv[0]; int e = rwe[0];
#pragma unroll
            for (int w = 1; w < TPB / 64; ++w)
                if (rwv[w] > v || (rwv[w] == v && rwe[w] < e)) { v = rwv[w]; e = rwe[w]; }
            fin[s] = e;
        }
        __syncthreads();
    }
    __syncthreads();

    // ---- epilogue: idx + gather quantize + diff (32 threads/sample, 4 dims each) ----
    {
        const int s  = tid >> 5;          // 0..15 (512 threads / 32)
        const int d0 = (tid & 31) * 4;
        const int e  = fin[s];
        float a = 0.0f;
#pragma unroll
        for (int j = 0; j < 4; ++j) {
            int d = d0 + j;
            float q = cm[(size_t)d * NEMB + e];
            float x = smp[(size_t)(s0 + s) * DIM + d];
            out_q[(size_t)(s0 + s) * DIM + d] = q;
            float t = x - q;
            a = fmaf(t, t, a);
        }
#pragma unroll
        for (int m = 1; m < 32; m <<= 1) a += __shfl_xor(a, m, 64);
        if ((tid & 31) == 0) out_diff[s0 + s] = a * (1.0f / DIM);
        if (tid < NS) out_idx[s0 + tid] = (float)fin[tid];
    }
}

extern "C" void kernel_launch(void* const* d_in, const int* in_sizes, int n_in,
                              void* d_out, int out_size, void* d_ws, size_t ws_size,
                              hipStream_t stream) {
    const float* smp = (const float*)d_in[0];   // [8192,128]
    const float* cm  = (const float*)d_in[1];   // [128,10000]

    float* out      = (float*)d_out;
    float* out_q    = out;
    float* out_idx  = out + (size_t)NSAMP * DIM;
    float* out_diff = out_idx + NSAMP;

    char* ws = (char*)d_ws;
    double* c2d = (double*)ws;                  // 80000 B
    float*  c2f = (float*)(ws + 80000);         // 40000 B

    prep_c2<<<(NEMB + PREP_TPB - 1) / PREP_TPB, PREP_TPB, 0, stream>>>(cm, c2d, c2f);
    vq_main32<<<NSAMP / NS, TPB, 0, stream>>>(cm, smp, c2f, c2d, out_q, out_idx, out_diff);
}